// Round 7
// baseline (401.409 us; speedup 1.0000x reference)
//
#include <hip/hip_runtime.h>

#define NB 512
#define ND 256
#define NKQ 65536
#define LCOLS 65539            // 3 + 65536
#define QTAIL 64000            // 65536 - 1536
#define TEMP 0.07f

// d_out element offsets (f32)
#define OFF_LABELS 33555968ull // 512*65539
#define OFF_SCORE  67111936ull // 2*512*65539
#define OFF_QUEUE  67115520ull // OFF_SCORE + 512*7

// DIAGNOSTIC ROUND: round-4 kernel exactly, with kgemm repeated 3x
// (deterministic, idempotent) so it surfaces in the rocprof top-5 table.
#define KGEMM_REPS 3

typedef __attribute__((ext_vector_type(8))) _Float16 half8;
typedef __attribute__((ext_vector_type(4))) float f32x4;

__device__ inline float wave_sum(float v) {
#pragma unroll
  for (int m = 1; m < 64; m <<= 1) v += __shfl_xor(v, m, 64);
  return v;
}

// ws layout (bytes):
// [0, 262144)          : fp16 normalized q, row-major [512][256]
// [262144, 786432)     : f32 normalized q
// [786432, 788480)     : pos_min[512]
// [788480, 794624)     : score_pos[512*3]
// [1048576, 5242880)   : stat partials [512 rows][512 blocks][4] f32

__global__ __launch_bounds__(256) void kprep(const float* __restrict__ query,
                                             const float* __restrict__ key_emb,
                                             float* __restrict__ out,
                                             _Float16* __restrict__ qf16,
                                             float* __restrict__ qf32) {
  int blk = blockIdx.x;
  if (blk < 512) {
    int w = threadIdx.x >> 6, l = threadIdx.x & 63;
    int r = blk * 4 + w;  // 0..2047
    const float* src = (r < NB) ? (query + (size_t)r * ND)
                                : (key_emb + (size_t)(r - NB) * ND);
    float x0 = src[l], x1 = src[l + 64], x2 = src[l + 128], x3 = src[l + 192];
    float ss = wave_sum(x0 * x0 + x1 * x1 + x2 * x2 + x3 * x3);
    float sc = 1.0f / fmaxf(sqrtf(ss), 1e-12f);
    x0 *= sc; x1 *= sc; x2 *= sc; x3 *= sc;
    if (r < NB) {
      float xs[4] = {x0, x1, x2, x3};
#pragma unroll
      for (int i = 0; i < 4; i++) {
        int d = l + i * 64;
        qf32[r * ND + d] = xs[i];
        qf16[r * ND + d] = (_Float16)xs[i];
      }
    } else {
      float* dst = out + OFF_QUEUE + (size_t)(QTAIL + r - NB) * ND;
      dst[l] = x0; dst[l + 64] = x1; dst[l + 128] = x2; dst[l + 192] = x3;
    }
  } else {
    f32x4 one = {1.f, 1.f, 1.f, 1.f};
    f32x4* lb = (f32x4*)(out + OFF_LABELS);
    const long total4 = (long)NB * LCOLS / 4;  // 8388992, exact
    long stride = (long)(2048 - 512) * 256;
    for (long i = (long)(blk - 512) * 256 + threadIdx.x; i < total4; i += stride)
      __builtin_nontemporal_store(one, lb + i);
  }
}

__global__ __launch_bounds__(64) void kpos(const float* __restrict__ qf32,
                                           float* __restrict__ out,
                                           float* __restrict__ posmin,
                                           float* __restrict__ spos) {
  int b = blockIdx.x, l = threadIdx.x;
  const float* q = qf32 + (size_t)b * ND;
  float q0 = q[l], q1 = q[l + 64], q2 = q[l + 128], q3 = q[l + 192];
  const float* kbase = out + OFF_QUEUE + (size_t)(QTAIL + b * 3) * ND;
  float sp[3];
#pragma unroll
  for (int j = 0; j < 3; j++) {
    const float* kp = kbase + (size_t)j * ND;
    float p = q0 * kp[l] + q1 * kp[l + 64] + q2 * kp[l + 128] + q3 * kp[l + 192];
    sp[j] = wave_sum(p);
  }
  if (l == 0) {
    float* lg = out + (size_t)b * LCOLS;
    float* scr = out + OFF_SCORE + (size_t)b * 7;
#pragma unroll
    for (int j = 0; j < 3; j++) {
      lg[j] = sp[j] / TEMP;
      scr[4 + j] = sp[j];
      spos[b * 3 + j] = sp[j];
    }
    posmin[b] = fminf(sp[0], fminf(sp[1], sp[2]));
  }
}

// round-4 kgemm, whole body repeated KGEMM_REPS times (idempotent stores).
__global__ __launch_bounds__(256) void kgemm(const float* __restrict__ queue,
                                             const _Float16* __restrict__ qf16,
                                             const float* __restrict__ posmin,
                                             float* __restrict__ out,
                                             float* __restrict__ partials) {
  __shared__ __align__(16) float otile[16 * 132];
  int blk = ((int)blockIdx.x & 7) * 64 + ((int)blockIdx.x >> 3);
  int nbase = blk * 128;
  int tid = threadIdx.x;

#pragma unroll 1
  for (int rep = 0; rep < KGEMM_REPS; rep++) {
    // Phase 0: fused FIFO copy (warms L2)
    const f32x4* qp = (const f32x4*)queue;
    f32x4* nq = (f32x4*)(out + OFF_QUEUE);
#pragma unroll
    for (int i = 0; i < 32; i++) {
      int idx = tid + i * 256;
      int row = idx >> 6, c4 = idx & 63;
      int grow = nbase + row;
      f32x4 v = qp[(size_t)grow * 64 + c4];
      if (grow >= 1536)
        __builtin_nontemporal_store(v, nq + (size_t)(grow - 1536) * 64 + c4);
    }

    // Phase 1: per-wave B fragments in registers
    int w = tid >> 6, l = tid & 63;
    int r = l & 15, g4 = l >> 4;
    uint4 bf0[8], bf1[8];
    {
      const float* qrow0 = queue + (size_t)(nbase + w * 32 + r) * ND;
      const float* qrow1 = qrow0 + 16 * ND;
#pragma unroll
      for (int kk = 0; kk < 8; kk++) {
        int k0 = kk * 32 + g4 * 8;
        f32x4 a0 = *(const f32x4*)(qrow0 + k0);
        f32x4 a1 = *(const f32x4*)(qrow0 + k0 + 4);
        f32x4 b0 = *(const f32x4*)(qrow1 + k0);
        f32x4 b1 = *(const f32x4*)(qrow1 + k0 + 4);
        half8 h0, h1;
        h0[0] = (_Float16)a0.x; h0[1] = (_Float16)a0.y; h0[2] = (_Float16)a0.z;
        h0[3] = (_Float16)a0.w; h0[4] = (_Float16)a1.x; h0[5] = (_Float16)a1.y;
        h0[6] = (_Float16)a1.z; h0[7] = (_Float16)a1.w;
        h1[0] = (_Float16)b0.x; h1[1] = (_Float16)b0.y; h1[2] = (_Float16)b0.z;
        h1[3] = (_Float16)b0.w; h1[4] = (_Float16)b1.x; h1[5] = (_Float16)b1.y;
        h1[6] = (_Float16)b1.z; h1[7] = (_Float16)b1.w;
        bf0[kk] = __builtin_bit_cast(uint4, h0);
        bf1[kk] = __builtin_bit_cast(uint4, h1);
      }
    }

    const uint4* ap = (const uint4*)qf16;
    const float inv_t = 1.0f / TEMP;
    int srow = tid >> 4, sc = (tid & 15) * 8;

    auto load_af = [&](uint4* dst, int mtv) {
#pragma unroll
      for (int kk = 0; kk < 8; kk++)
        dst[kk] = ap[(size_t)(mtv * 16 + r) * 32 + kk * 4 + g4];
    };

    auto body = [&](const uint4* af, int mt) {
      f32x4 acc0 = {0.f, 0.f, 0.f, 0.f}, acc1 = {0.f, 0.f, 0.f, 0.f};
#pragma unroll
      for (int kk = 0; kk < 8; kk++) {
        acc0 = __builtin_amdgcn_mfma_f32_16x16x32_f16(
            __builtin_bit_cast(half8, af[kk]), __builtin_bit_cast(half8, bf0[kk]),
            acc0, 0, 0, 0);
        acc1 = __builtin_amdgcn_mfma_f32_16x16x32_f16(
            __builtin_bit_cast(half8, af[kk]), __builtin_bit_cast(half8, bf1[kk]),
            acc1, 0, 0, 0);
      }
      __syncthreads();
#pragma unroll
      for (int j = 0; j < 4; j++) {
        otile[(g4 * 4 + j) * 132 + w * 32 + r] = acc0[j];
        otile[(g4 * 4 + j) * 132 + w * 32 + 16 + r] = acc1[j];
      }
      __syncthreads();
#pragma unroll
      for (int i = 0; i < 8; i++) {
        int idx = tid + i * 256;
        int orow = idx >> 7, ocol = idx & 127;
        float v = otile[orow * 132 + ocol];
        out[(size_t)(mt * 16 + orow) * LCOLS + 3 + nbase + ocol] = v * inv_t;
      }
      f32x4 s0 = *(const f32x4*)&otile[srow * 132 + sc];
      f32x4 s1 = *(const f32x4*)&otile[srow * 132 + sc + 4];
      float pm = posmin[mt * 16 + srow];
      float s = s0.x + s0.y + s0.z + s0.w + s1.x + s1.y + s1.z + s1.w;
      float s2 = s0.x * s0.x + s0.y * s0.y + s0.z * s0.z + s0.w * s0.w +
                 s1.x * s1.x + s1.y * s1.y + s1.z * s1.z + s1.w * s1.w;
      float mx = fmaxf(fmaxf(fmaxf(s0.x, s0.y), fmaxf(s0.z, s0.w)),
                       fmaxf(fmaxf(s1.x, s1.y), fmaxf(s1.z, s1.w)));
      float c = (s0.x > pm ? 1.f : 0.f) + (s0.y > pm ? 1.f : 0.f) +
                (s0.z > pm ? 1.f : 0.f) + (s0.w > pm ? 1.f : 0.f) +
                (s1.x > pm ? 1.f : 0.f) + (s1.y > pm ? 1.f : 0.f) +
                (s1.z > pm ? 1.f : 0.f) + (s1.w > pm ? 1.f : 0.f);
#pragma unroll
      for (int m = 1; m < 16; m <<= 1) {
        s += __shfl_xor(s, m, 64);
        s2 += __shfl_xor(s2, m, 64);
        c += __shfl_xor(c, m, 64);
        mx = fmaxf(mx, __shfl_xor(mx, m, 64));
      }
      if ((tid & 15) == 0) {
        f32x4 p = {s, s2, mx, c};
        *(f32x4*)&partials[((size_t)(mt * 16 + srow) * 512 + blk) * 4] = p;
      }
    };

    uint4 afA[8], afB[8];
    load_af(afA, 0);
#pragma unroll 1
    for (int mt2 = 0; mt2 < 16; mt2++) {
      int mt = mt2 * 2;
      load_af(afB, mt + 1);
      body(afA, mt);
      if (mt2 < 15) load_af(afA, mt + 2);
      body(afB, mt + 1);
    }
    __syncthreads();
  }
}

__global__ __launch_bounds__(256) void kreduce(const float* __restrict__ partials,
                                               const float* __restrict__ spos,
                                               float* __restrict__ out) {
  int b = blockIdx.x, tid = threadIdx.x;
  const f32x4* p = (const f32x4*)(partials + (size_t)b * 2048);
  float s = 0.f, s2 = 0.f, mx = -2.f, c = 0.f;
#pragma unroll
  for (int i = 0; i < 2; i++) {
    f32x4 v = p[tid + i * 256];
    s += v.x; s2 += v.y; mx = fmaxf(mx, v.z); c += v.w;
  }
#pragma unroll
  for (int m = 1; m < 64; m <<= 1) {
    s += __shfl_xor(s, m, 64);
    s2 += __shfl_xor(s2, m, 64);
    c += __shfl_xor(c, m, 64);
    mx = fmaxf(mx, __shfl_xor(mx, m, 64));
  }
  __shared__ float red[4][4];
  int w = tid >> 6, l = tid & 63;
  if (l == 0) { red[w][0] = s; red[w][1] = s2; red[w][2] = c; red[w][3] = mx; }
  __syncthreads();
  if (tid == 0) {
    float S = 0, S2 = 0, C = 0, M = -2.f;
    for (int i = 0; i < 4; i++) {
      S += red[i][0]; S2 += red[i][1]; C += red[i][2]; M = fmaxf(M, red[i][3]);
    }
    float mean = S / (float)NKQ;
    float var = (S2 - S * S / (float)NKQ) / (float)(NKQ - 1);  // ddof=1
    float cp = 0.f;
    for (int j = 0; j < 3; j++) cp += (M > spos[b * 3 + j]) ? 1.f : 0.f;
    float* scr = out + OFF_SCORE + (size_t)b * 7;
    scr[0] = mean; scr[1] = var; scr[2] = C; scr[3] = cp;
  }
}

extern "C" void kernel_launch(void* const* d_in, const int* in_sizes, int n_in,
                              void* d_out, int out_size, void* d_ws, size_t ws_size,
                              hipStream_t stream) {
  const float* query = (const float*)d_in[0];
  const float* key_emb = (const float*)d_in[1];
  const float* queue = (const float*)d_in[2];
  float* out = (float*)d_out;
  _Float16* qf16 = (_Float16*)d_ws;
  float* qf32 = (float*)((char*)d_ws + 262144);
  float* posmin = (float*)((char*)d_ws + 786432);
  float* spos = (float*)((char*)d_ws + 788480);
  float* partials = (float*)((char*)d_ws + 1048576);

  kprep<<<2048, 256, 0, stream>>>(query, key_emb, out, qf16, qf32);
  kpos<<<512, 64, 0, stream>>>(qf32, out, posmin, spos);
  kgemm<<<512, 256, 0, stream>>>(queue, qf16, posmin, out, partials);
  kreduce<<<512, 256, 0, stream>>>(partials, spos, out);
}

// Round 8
// 216.701 us; speedup vs baseline: 1.8524x; 1.8524x over previous
//
#include <hip/hip_runtime.h>

#define NB 512
#define ND 256
#define NKQ 65536
#define LCOLS 65539            // 3 + 65536
#define QTAIL 64000            // 65536 - 1536
#define TEMP 0.07f

// d_out element offsets (f32)
#define OFF_LABELS 33555968ull // 512*65539
#define OFF_SCORE  67111936ull // 2*512*65539
#define OFF_QUEUE  67115520ull // OFF_SCORE + 512*7

typedef __attribute__((ext_vector_type(8))) _Float16 half8;
typedef __attribute__((ext_vector_type(4))) float f32x4;

__device__ inline float wave_sum(float v) {
#pragma unroll
  for (int m = 1; m < 64; m <<= 1) v += __shfl_xor(v, m, 64);
  return v;
}

// ws layout (bytes):
// [0, 262144)          : fp16 normalized q, row-major [512][256]
// [262144, 786432)     : f32 normalized q
// [786432, 788480)     : pos_min[512]
// [788480, 794624)     : score_pos[512*3]
// [1048576, 9437184)   : stat partials f32x4 [512 rows][1024 col-blocks]

__global__ __launch_bounds__(256) void kprep(const float* __restrict__ query,
                                             const float* __restrict__ key_emb,
                                             float* __restrict__ out,
                                             _Float16* __restrict__ qf16,
                                             float* __restrict__ qf32) {
  int blk = blockIdx.x;
  if (blk < 512) {
    int w = threadIdx.x >> 6, l = threadIdx.x & 63;
    int r = blk * 4 + w;  // 0..2047
    const float* src = (r < NB) ? (query + (size_t)r * ND)
                                : (key_emb + (size_t)(r - NB) * ND);
    float x0 = src[l], x1 = src[l + 64], x2 = src[l + 128], x3 = src[l + 192];
    float ss = wave_sum(x0 * x0 + x1 * x1 + x2 * x2 + x3 * x3);
    float sc = 1.0f / fmaxf(sqrtf(ss), 1e-12f);
    x0 *= sc; x1 *= sc; x2 *= sc; x3 *= sc;
    if (r < NB) {
      float xs[4] = {x0, x1, x2, x3};
#pragma unroll
      for (int i = 0; i < 4; i++) {
        int d = l + i * 64;
        qf32[r * ND + d] = xs[i];
        qf16[r * ND + d] = (_Float16)xs[i];
      }
    } else {
      float* dst = out + OFF_QUEUE + (size_t)(QTAIL + r - NB) * ND;
      dst[l] = x0; dst[l + 64] = x1; dst[l + 128] = x2; dst[l + 192] = x3;
    }
  } else {
    f32x4 one = {1.f, 1.f, 1.f, 1.f};
    f32x4* lb = (f32x4*)(out + OFF_LABELS);
    const long total4 = (long)NB * LCOLS / 4;  // 8388992, exact
    long stride = (long)(2048 - 512) * 256;
    for (long i = (long)(blk - 512) * 256 + threadIdx.x; i < total4; i += stride)
      __builtin_nontemporal_store(one, lb + i);
  }
}

__global__ __launch_bounds__(64) void kpos(const float* __restrict__ qf32,
                                           float* __restrict__ out,
                                           float* __restrict__ posmin,
                                           float* __restrict__ spos) {
  int b = blockIdx.x, l = threadIdx.x;
  const float* q = qf32 + (size_t)b * ND;
  float q0 = q[l], q1 = q[l + 64], q2 = q[l + 128], q3 = q[l + 192];
  const float* kbase = out + OFF_QUEUE + (size_t)(QTAIL + b * 3) * ND;
  float sp[3];
#pragma unroll
  for (int j = 0; j < 3; j++) {
    const float* kp = kbase + (size_t)j * ND;
    float p = q0 * kp[l] + q1 * kp[l + 64] + q2 * kp[l + 128] + q3 * kp[l + 192];
    sp[j] = wave_sum(p);
  }
  if (l == 0) {
    float* lg = out + (size_t)b * LCOLS;
    float* scr = out + OFF_SCORE + (size_t)b * 7;
#pragma unroll
    for (int j = 0; j < 3; j++) {
      lg[j] = sp[j] / TEMP;
      scr[4 + j] = sp[j];
      spos[b * 3 + j] = sp[j];
    }
    posmin[b] = fminf(sp[0], fminf(sp[1], sp[2]));
  }
}

// Occupancy-first kgemm: 2048 blocks = 1024 col-blocks (64 cols) x 2 m-splits
// (16 m-tiles each). Per wave: 16 cols (bf 32 VGPRs), single af buffer, one
// acc. launch_bounds(256,4) forces <=128 VGPRs -> 4 waves/SIMD.
__global__ __launch_bounds__(256, 4) void kgemm(const float* __restrict__ queue,
                                                const _Float16* __restrict__ qf16,
                                                const float* __restrict__ posmin,
                                                float* __restrict__ out,
                                                float* __restrict__ partials) {
  __shared__ __align__(16) float otile[16 * 68];  // 16 rows x 64 cols, pad 68
  // XCD grouping: xcd owns 128 contiguous col-blocks; both m-splits local.
  int xcd = (int)blockIdx.x & 7;
  int idx = (int)blockIdx.x >> 3;       // 0..255
  int cb = xcd * 128 + (idx >> 1);      // col-block 0..1023
  int ms = idx & 1;                     // m-split
  int nbase = cb * 64;
  int mt0 = ms * 16;
  int tid = threadIdx.x;
  int w = tid >> 6, l = tid & 63;
  int r = l & 15, g4 = l >> 4;

  // Phase 0 (m-split 0 only): fused FIFO copy of this col-block's 64 rows
  if (ms == 0) {
    const f32x4* qp = (const f32x4*)queue;
    f32x4* nq = (f32x4*)(out + OFF_QUEUE);
#pragma unroll
    for (int i = 0; i < 16; i++) {
      int t = tid + i * 256;            // 64 rows * 64 f32x4
      int row = t >> 6, c4 = t & 63;
      int grow = nbase + row;
      f32x4 v = qp[(size_t)grow * 64 + c4];
      if (grow >= 1536)
        __builtin_nontemporal_store(v, nq + (size_t)(grow - 1536) * 64 + c4);
    }
  }

  // Phase 1: per-wave B fragments (16 cols per wave) from L2/L3-hot queue
  uint4 bf[8];
  {
    const float* qrow = queue + (size_t)(nbase + w * 16 + r) * ND;
#pragma unroll
    for (int kk = 0; kk < 8; kk++) {
      int k0 = kk * 32 + g4 * 8;
      f32x4 a0 = *(const f32x4*)(qrow + k0);
      f32x4 a1 = *(const f32x4*)(qrow + k0 + 4);
      half8 h;
      h[0] = (_Float16)a0.x; h[1] = (_Float16)a0.y; h[2] = (_Float16)a0.z;
      h[3] = (_Float16)a0.w; h[4] = (_Float16)a1.x; h[5] = (_Float16)a1.y;
      h[6] = (_Float16)a1.z; h[7] = (_Float16)a1.w;
      bf[kk] = __builtin_bit_cast(uint4, h);
    }
  }

  const uint4* ap = (const uint4*)qf16;  // row-major: idx = row*32 + kk*4 + g4
  const float inv_t = 1.0f / TEMP;
  int srow = tid >> 4, sc = (tid & 15) * 4;  // stats: 16 lanes/row, 4 cols/lane

#pragma unroll 1
  for (int mt = mt0; mt < mt0 + 16; mt++) {
    uint4 af[8];
#pragma unroll
    for (int kk = 0; kk < 8; kk++)
      af[kk] = ap[(size_t)(mt * 16 + r) * 32 + kk * 4 + g4];
    f32x4 acc = {0.f, 0.f, 0.f, 0.f};
#pragma unroll
    for (int kk = 0; kk < 8; kk++)
      acc = __builtin_amdgcn_mfma_f32_16x16x32_f16(
          __builtin_bit_cast(half8, af[kk]), __builtin_bit_cast(half8, bf[kk]),
          acc, 0, 0, 0);
    __syncthreads();  // previous iteration's otile readers done
    // D layout: col = lane&15 (our n), row = (lane>>4)*4 + j
#pragma unroll
    for (int j = 0; j < 4; j++)
      otile[(g4 * 4 + j) * 68 + w * 16 + r] = acc[j];
    __syncthreads();
    // logits: 64 consecutive floats (256B) per wave-instr, 4 rows per i
#pragma unroll
    for (int i = 0; i < 4; i++) {
      int t = tid + i * 256;
      int orow = t >> 6, ocol = t & 63;
      float v = otile[orow * 68 + ocol];
      out[(size_t)(mt * 16 + orow) * LCOLS + 3 + nbase + ocol] = v * inv_t;
    }
    // stats over this block's 64 cols
    f32x4 sv = *(const f32x4*)&otile[srow * 68 + sc];
    float pm = posmin[mt * 16 + srow];
    float s = sv.x + sv.y + sv.z + sv.w;
    float s2 = sv.x * sv.x + sv.y * sv.y + sv.z * sv.z + sv.w * sv.w;
    float mx = fmaxf(fmaxf(sv.x, sv.y), fmaxf(sv.z, sv.w));
    float c = (sv.x > pm ? 1.f : 0.f) + (sv.y > pm ? 1.f : 0.f) +
              (sv.z > pm ? 1.f : 0.f) + (sv.w > pm ? 1.f : 0.f);
#pragma unroll
    for (int m = 1; m < 16; m <<= 1) {
      s += __shfl_xor(s, m, 64);
      s2 += __shfl_xor(s2, m, 64);
      c += __shfl_xor(c, m, 64);
      mx = fmaxf(mx, __shfl_xor(mx, m, 64));
    }
    if ((tid & 15) == 0) {
      f32x4 p = {s, s2, mx, c};
      *(f32x4*)&partials[((size_t)(mt * 16 + srow) * 1024 + cb) * 4] = p;
    }
  }
}

// combine 1024 per-col-block partials per row -> score[:, 0:4]
__global__ __launch_bounds__(256) void kreduce(const float* __restrict__ partials,
                                               const float* __restrict__ spos,
                                               float* __restrict__ out) {
  int b = blockIdx.x, tid = threadIdx.x;
  const f32x4* p = (const f32x4*)(partials + (size_t)b * 4096);
  float s = 0.f, s2 = 0.f, mx = -2.f, c = 0.f;
#pragma unroll
  for (int i = 0; i < 4; i++) {
    f32x4 v = p[tid + i * 256];
    s += v.x; s2 += v.y; mx = fmaxf(mx, v.z); c += v.w;
  }
#pragma unroll
  for (int m = 1; m < 64; m <<= 1) {
    s += __shfl_xor(s, m, 64);
    s2 += __shfl_xor(s2, m, 64);
    c += __shfl_xor(c, m, 64);
    mx = fmaxf(mx, __shfl_xor(mx, m, 64));
  }
  __shared__ float red[4][4];
  int w = tid >> 6, l = tid & 63;
  if (l == 0) { red[w][0] = s; red[w][1] = s2; red[w][2] = c; red[w][3] = mx; }
  __syncthreads();
  if (tid == 0) {
    float S = 0, S2 = 0, C = 0, M = -2.f;
    for (int i = 0; i < 4; i++) {
      S += red[i][0]; S2 += red[i][1]; C += red[i][2]; M = fmaxf(M, red[i][3]);
    }
    float mean = S / (float)NKQ;
    float var = (S2 - S * S / (float)NKQ) / (float)(NKQ - 1);  // ddof=1
    float cp = 0.f;
    for (int j = 0; j < 3; j++) cp += (M > spos[b * 3 + j]) ? 1.f : 0.f;
    float* scr = out + OFF_SCORE + (size_t)b * 7;
    scr[0] = mean; scr[1] = var; scr[2] = C; scr[3] = cp;
  }
}

extern "C" void kernel_launch(void* const* d_in, const int* in_sizes, int n_in,
                              void* d_out, int out_size, void* d_ws, size_t ws_size,
                              hipStream_t stream) {
  const float* query = (const float*)d_in[0];
  const float* key_emb = (const float*)d_in[1];
  const float* queue = (const float*)d_in[2];
  float* out = (float*)d_out;
  _Float16* qf16 = (_Float16*)d_ws;
  float* qf32 = (float*)((char*)d_ws + 262144);
  float* posmin = (float*)((char*)d_ws + 786432);
  float* spos = (float*)((char*)d_ws + 788480);
  float* partials = (float*)((char*)d_ws + 1048576);

  kprep<<<2048, 256, 0, stream>>>(query, key_emb, out, qf16, qf32);
  kpos<<<512, 64, 0, stream>>>(qf32, out, posmin, spos);
  kgemm<<<2048, 256, 0, stream>>>(queue, qf16, posmin, out, partials);
  kreduce<<<512, 256, 0, stream>>>(partials, spos, out);
}

// Round 9
// 148.299 us; speedup vs baseline: 2.7068x; 1.4612x over previous
//
#include <hip/hip_runtime.h>

#define NB 512
#define ND 256
#define NKQ 65536
#define LCOLS 65539            // 3 + 65536
#define QTAIL 64000            // 65536 - 1536
#define TEMP 0.07f

// d_out element offsets (f32)
#define OFF_LABELS 33555968ull // 512*65539
#define OFF_SCORE  67111936ull // 2*512*65539
#define OFF_QUEUE  67115520ull // OFF_SCORE + 512*7

typedef __attribute__((ext_vector_type(8))) _Float16 half8;
typedef __attribute__((ext_vector_type(4))) float f32x4;
typedef __attribute__((ext_vector_type(4), aligned(4))) float f32x4u;  // unaligned store
typedef __attribute__((ext_vector_type(4))) unsigned short us4;

__device__ inline float wave_sum(float v) {
#pragma unroll
  for (int m = 1; m < 64; m <<= 1) v += __shfl_xor(v, m, 64);
  return v;
}
__device__ inline unsigned short f2bf(float x) {  // RNE f32->bf16
  union { float f; unsigned u; } v; v.f = x;
  unsigned r = (v.u + 0x7FFF + ((v.u >> 16) & 1)) >> 16;
  return (unsigned short)r;
}
__device__ inline float bf2f(unsigned short h) {
  union { unsigned u; float f; } v; v.u = ((unsigned)h) << 16;
  return v.f;
}

// ws layout (bytes):
// [0, 262144)          : fp16 normalized q, row-major [512][256]
// [262144, 786432)     : f32 normalized q
// [786432, 788480)     : pos_min[512]
// [788480, 794624)     : score_pos[512*3]
// [1048576, 9437184)   : stat partials bf16x4 [2048 groups][512 rows]

__global__ __launch_bounds__(256) void kprep(const float* __restrict__ query,
                                             const float* __restrict__ key_emb,
                                             float* __restrict__ out,
                                             _Float16* __restrict__ qf16,
                                             float* __restrict__ qf32) {
  int blk = blockIdx.x;
  if (blk < 512) {
    int w = threadIdx.x >> 6, l = threadIdx.x & 63;
    int r = blk * 4 + w;  // 0..2047
    const float* src = (r < NB) ? (query + (size_t)r * ND)
                                : (key_emb + (size_t)(r - NB) * ND);
    float x0 = src[l], x1 = src[l + 64], x2 = src[l + 128], x3 = src[l + 192];
    float ss = wave_sum(x0 * x0 + x1 * x1 + x2 * x2 + x3 * x3);
    float sc = 1.0f / fmaxf(sqrtf(ss), 1e-12f);
    x0 *= sc; x1 *= sc; x2 *= sc; x3 *= sc;
    if (r < NB) {
      float xs[4] = {x0, x1, x2, x3};
#pragma unroll
      for (int i = 0; i < 4; i++) {
        int d = l + i * 64;
        qf32[r * ND + d] = xs[i];
        qf16[r * ND + d] = (_Float16)xs[i];
      }
    } else {
      float* dst = out + OFF_QUEUE + (size_t)(QTAIL + r - NB) * ND;
      dst[l] = x0; dst[l + 64] = x1; dst[l + 128] = x2; dst[l + 192] = x3;
    }
  } else {
    f32x4 one = {1.f, 1.f, 1.f, 1.f};
    f32x4* lb = (f32x4*)(out + OFF_LABELS);
    const long total4 = (long)NB * LCOLS / 4;  // 8388992, exact
    long stride = (long)(2048 - 512) * 256;
    for (long i = (long)(blk - 512) * 256 + threadIdx.x; i < total4; i += stride)
      __builtin_nontemporal_store(one, lb + i);
  }
}

__global__ __launch_bounds__(64) void kpos(const float* __restrict__ qf32,
                                           float* __restrict__ out,
                                           float* __restrict__ posmin,
                                           float* __restrict__ spos) {
  int b = blockIdx.x, l = threadIdx.x;
  const float* q = qf32 + (size_t)b * ND;
  float q0 = q[l], q1 = q[l + 64], q2 = q[l + 128], q3 = q[l + 192];
  const float* kbase = out + OFF_QUEUE + (size_t)(QTAIL + b * 3) * ND;
  float sp[3];
#pragma unroll
  for (int j = 0; j < 3; j++) {
    const float* kp = kbase + (size_t)j * ND;
    float p = q0 * kp[l] + q1 * kp[l + 64] + q2 * kp[l + 128] + q3 * kp[l + 192];
    sp[j] = wave_sum(p);
  }
  if (l == 0) {
    float* lg = out + (size_t)b * LCOLS;
    float* scr = out + OFF_SCORE + (size_t)b * 7;
#pragma unroll
    for (int j = 0; j < 3; j++) {
      lg[j] = sp[j] / TEMP;
      scr[4 + j] = sp[j];
      spos[b * 3 + j] = sp[j];
    }
    posmin[b] = fminf(sp[0], fminf(sp[1], sp[2]));
  }
}

// Swapped-operand GEMM: A=queue fragment (n side), B=q fragment (m side).
// D: col(lane&15)=m, row((lane>>4)*4+j)=n -> each lane's 4 acc regs are 4
// consecutive logits columns of one row => direct 16B/lane stores.
// NO LDS, NO barriers in the whole kernel.
// 1024 blocks = 512 col-blocks (128 n) x 2 m-splits (16 m-tiles each).
__global__ __launch_bounds__(256, 4) void kgemm(const float* __restrict__ queue,
                                                const _Float16* __restrict__ qf16,
                                                const float* __restrict__ posmin,
                                                float* __restrict__ out,
                                                unsigned short* __restrict__ partials) {
  int b = blockIdx.x;
  int xcd = b & 7, idx = b >> 3;        // XCD grouping (1024 % 8 == 0)
  int cb = xcd * 64 + (idx >> 1);       // col-block 0..511
  int ms = idx & 1;                     // m-split
  int nbase = cb * 128;
  int tid = threadIdx.x;
  int w = tid >> 6, l = tid & 63;
  int r = l & 15, g4 = l >> 4;

  // Phase 0 (ms==0 only): fused FIFO copy of this col-block's 128 queue rows
  if (ms == 0) {
    const f32x4* qp = (const f32x4*)queue;
    f32x4* nq = (f32x4*)(out + OFF_QUEUE);
#pragma unroll
    for (int i = 0; i < 32; i++) {
      int t = tid + i * 256;            // 128 rows * 64 f32x4
      int row = t >> 6, c4 = t & 63;
      int grow = nbase + row;
      f32x4 v = qp[(size_t)grow * 64 + c4];
      if (grow >= 1536)
        __builtin_nontemporal_store(v, nq + (size_t)(grow - 1536) * 64 + c4);
    }
  }

  // Phase 1: A fragments = this wave's 32 queue rows (2 tiles of 16), f32->f16
  uint4 af[2][8];
#pragma unroll
  for (int t = 0; t < 2; t++) {
    const float* qrow = queue + (size_t)(nbase + w * 32 + t * 16 + r) * ND;
#pragma unroll
    for (int kk = 0; kk < 8; kk++) {
      int k0 = kk * 32 + g4 * 8;
      f32x4 a0 = *(const f32x4*)(qrow + k0);
      f32x4 a1 = *(const f32x4*)(qrow + k0 + 4);
      half8 h;
      h[0] = (_Float16)a0.x; h[1] = (_Float16)a0.y; h[2] = (_Float16)a0.z;
      h[3] = (_Float16)a0.w; h[4] = (_Float16)a1.x; h[5] = (_Float16)a1.y;
      h[6] = (_Float16)a1.z; h[7] = (_Float16)a1.w;
      af[t][kk] = __builtin_bit_cast(uint4, h);
    }
  }

  const uint4* ap = (const uint4*)qf16;  // B frag: idx = row*32 + kk*4 + g4
  const float inv_t = 1.0f / TEMP;
  int mt0 = ms * 16;
  // n-bases of this lane's two store vectors
  size_t n0 = nbase + w * 32 + g4 * 4;

#pragma unroll 1
  for (int mt = mt0; mt < mt0 + 16; mt++) {
    uint4 bf[8];
#pragma unroll
    for (int kk = 0; kk < 8; kk++)
      bf[kk] = ap[(size_t)(mt * 16 + r) * 32 + kk * 4 + g4];
    f32x4 acc0 = {0.f, 0.f, 0.f, 0.f}, acc1 = {0.f, 0.f, 0.f, 0.f};
#pragma unroll
    for (int kk = 0; kk < 8; kk++) {
      acc0 = __builtin_amdgcn_mfma_f32_16x16x32_f16(
          __builtin_bit_cast(half8, af[0][kk]), __builtin_bit_cast(half8, bf[kk]),
          acc0, 0, 0, 0);
      acc1 = __builtin_amdgcn_mfma_f32_16x16x32_f16(
          __builtin_bit_cast(half8, af[1][kk]), __builtin_bit_cast(half8, bf[kk]),
          acc1, 0, 0, 0);
    }
    int m = mt * 16 + r;
    float* rowp = out + (size_t)m * LCOLS + 3;
    f32x4 v0 = acc0 * inv_t, v1 = acc1 * inv_t;
    *(f32x4u*)(rowp + n0) = v0;
    *(f32x4u*)(rowp + n0 + 16) = v1;
    // stats: all 8 values belong to row m; reduce across g4 groups (xor 16,32)
    float s = acc0.x + acc0.y + acc0.z + acc0.w +
              acc1.x + acc1.y + acc1.z + acc1.w;
    float s2 = acc0.x * acc0.x + acc0.y * acc0.y + acc0.z * acc0.z +
               acc0.w * acc0.w + acc1.x * acc1.x + acc1.y * acc1.y +
               acc1.z * acc1.z + acc1.w * acc1.w;
    float mx = fmaxf(fmaxf(fmaxf(acc0.x, acc0.y), fmaxf(acc0.z, acc0.w)),
                     fmaxf(fmaxf(acc1.x, acc1.y), fmaxf(acc1.z, acc1.w)));
    float pm = posmin[m];
    float c = (acc0.x > pm ? 1.f : 0.f) + (acc0.y > pm ? 1.f : 0.f) +
              (acc0.z > pm ? 1.f : 0.f) + (acc0.w > pm ? 1.f : 0.f) +
              (acc1.x > pm ? 1.f : 0.f) + (acc1.y > pm ? 1.f : 0.f) +
              (acc1.z > pm ? 1.f : 0.f) + (acc1.w > pm ? 1.f : 0.f);
#pragma unroll
    for (int sh = 16; sh < 64; sh <<= 1) {
      s += __shfl_xor(s, sh, 64);
      s2 += __shfl_xor(s2, sh, 64);
      c += __shfl_xor(c, sh, 64);
      mx = fmaxf(mx, __shfl_xor(mx, sh, 64));
    }
    if (g4 == 0) {
      us4 p = {f2bf(s), f2bf(s2), f2bf(mx), f2bf(c)};
      // [group][row]: 16 lanes write 128B contiguous
      *(us4*)&partials[((size_t)(cb * 4 + w) * 512 + m) * 4] = p;
    }
  }
}

// combine 2048 bf16 partials per row -> score[:, 0:4]. 64 blocks x 8 rows.
__global__ __launch_bounds__(256) void kreduce(const unsigned short* __restrict__ partials,
                                               const float* __restrict__ spos,
                                               float* __restrict__ out) {
  int r0 = blockIdx.x * 8;
  int tid = threadIdx.x;
  float s[8], s2[8], mx[8], c[8];
#pragma unroll
  for (int j = 0; j < 8; j++) { s[j] = 0.f; s2[j] = 0.f; mx[j] = -2.f; c[j] = 0.f; }
  for (int g = tid; g < 2048; g += 256) {
    const unsigned short* pg = partials + ((size_t)g * 512 + r0) * 4;
#pragma unroll
    for (int j = 0; j < 8; j++) {
      us4 v = *(const us4*)(pg + j * 4);
      s[j] += bf2f(v.x); s2[j] += bf2f(v.y);
      mx[j] = fmaxf(mx[j], bf2f(v.z)); c[j] += bf2f(v.w);
    }
  }
#pragma unroll
  for (int j = 0; j < 8; j++) {
#pragma unroll
    for (int m = 1; m < 64; m <<= 1) {
      s[j] += __shfl_xor(s[j], m, 64);
      s2[j] += __shfl_xor(s2[j], m, 64);
      c[j] += __shfl_xor(c[j], m, 64);
      mx[j] = fmaxf(mx[j], __shfl_xor(mx[j], m, 64));
    }
  }
  __shared__ float red[4][8][4];
  int w = tid >> 6, l = tid & 63;
  if (l == 0) {
#pragma unroll
    for (int j = 0; j < 8; j++) {
      red[w][j][0] = s[j]; red[w][j][1] = s2[j];
      red[w][j][2] = c[j]; red[w][j][3] = mx[j];
    }
  }
  __syncthreads();
  if (tid < 8) {
    int row = r0 + tid;
    float S = 0.f, S2 = 0.f, C = 0.f, M = -2.f;
#pragma unroll
    for (int w2 = 0; w2 < 4; w2++) {
      S += red[w2][tid][0]; S2 += red[w2][tid][1];
      C += red[w2][tid][2]; M = fmaxf(M, red[w2][tid][3]);
    }
    float mean = S / (float)NKQ;
    float var = (S2 - S * S / (float)NKQ) / (float)(NKQ - 1);  // ddof=1
    float cp = 0.f;
#pragma unroll
    for (int j = 0; j < 3; j++) cp += (M > spos[row * 3 + j]) ? 1.f : 0.f;
    float* scr = out + OFF_SCORE + (size_t)row * 7;
    scr[0] = mean; scr[1] = var; scr[2] = C; scr[3] = cp;
  }
}

extern "C" void kernel_launch(void* const* d_in, const int* in_sizes, int n_in,
                              void* d_out, int out_size, void* d_ws, size_t ws_size,
                              hipStream_t stream) {
  const float* query = (const float*)d_in[0];
  const float* key_emb = (const float*)d_in[1];
  const float* queue = (const float*)d_in[2];
  float* out = (float*)d_out;
  _Float16* qf16 = (_Float16*)d_ws;
  float* qf32 = (float*)((char*)d_ws + 262144);
  float* posmin = (float*)((char*)d_ws + 786432);
  float* spos = (float*)((char*)d_ws + 788480);
  unsigned short* partials = (unsigned short*)((char*)d_ws + 1048576);

  kprep<<<2048, 256, 0, stream>>>(query, key_emb, out, qf16, qf32);
  kpos<<<512, 64, 0, stream>>>(qf32, out, posmin, spos);
  kgemm<<<1024, 256, 0, stream>>>(queue, qf16, posmin, out, partials);
  kreduce<<<64, 256, 0, stream>>>(partials, spos, out);
}

// Round 10
// 102.207 us; speedup vs baseline: 3.9274x; 1.4510x over previous
//
#include <hip/hip_runtime.h>

#define NB 512
#define ND 256
#define NKQ 65536
#define LCOLS 65539            // 3 + 65536
#define QTAIL 64000            // 65536 - 1536
#define TEMP 0.07f

// d_out element offsets (f32)
#define OFF_LABELS 33555968ull // 512*65539
#define OFF_SCORE  67111936ull // 2*512*65539
#define OFF_QUEUE  67115520ull // OFF_SCORE + 512*7

typedef __attribute__((ext_vector_type(8))) _Float16 half8;
typedef __attribute__((ext_vector_type(4))) float f32x4;
typedef __attribute__((ext_vector_type(4))) unsigned short us4;

__device__ inline float wave_sum(float v) {
#pragma unroll
  for (int m = 1; m < 64; m <<= 1) v += __shfl_xor(v, m, 64);
  return v;
}
__device__ inline unsigned short f2bf(float x) {  // RNE f32->bf16
  union { float f; unsigned u; } v; v.f = x;
  unsigned r = (v.u + 0x7FFF + ((v.u >> 16) & 1)) >> 16;
  return (unsigned short)r;
}
__device__ inline float bf2f(unsigned short h) {
  union { unsigned u; float f; } v; v.u = ((unsigned)h) << 16;
  return v.f;
}

// ws layout (bytes):
// [0, 262144)          : fp16 normalized q in MFMA FRAGMENT ORDER:
//                        half index ((mt*8+kk)*64 + g4*16 + rr)*8 + j
//                        = q[mt*16+rr][kk*32+g4*8+j]
// [262144, 786432)     : f32 normalized q (row-major, for kpos)
// [786432, 788480)     : pos_min[512]
// [788480, 794624)     : score_pos[512*3]
// [1048576, 9437184)   : stat partials bf16x4 [2048 groups][512 rows]

__global__ __launch_bounds__(256) void kprep(const float* __restrict__ query,
                                             const float* __restrict__ key_emb,
                                             float* __restrict__ out,
                                             _Float16* __restrict__ qfrag,
                                             float* __restrict__ qf32) {
  int blk = blockIdx.x;
  if (blk < 512) {
    int w = threadIdx.x >> 6, l = threadIdx.x & 63;
    int r = blk * 4 + w;  // 0..2047
    const float* src = (r < NB) ? (query + (size_t)r * ND)
                                : (key_emb + (size_t)(r - NB) * ND);
    float x0 = src[l], x1 = src[l + 64], x2 = src[l + 128], x3 = src[l + 192];
    float ss = wave_sum(x0 * x0 + x1 * x1 + x2 * x2 + x3 * x3);
    float sc = 1.0f / fmaxf(sqrtf(ss), 1e-12f);
    x0 *= sc; x1 *= sc; x2 *= sc; x3 *= sc;
    if (r < NB) {
      float xs[4] = {x0, x1, x2, x3};
      int mt = r >> 4, rr = r & 15;
#pragma unroll
      for (int i = 0; i < 4; i++) {
        int d = l + i * 64;
        qf32[r * ND + d] = xs[i];
        int kk = d >> 5, g4 = (d >> 3) & 3, j = d & 7;
        qfrag[((size_t)(mt * 8 + kk) * 64 + g4 * 16 + rr) * 8 + j] =
            (_Float16)xs[i];
      }
    } else {
      float* dst = out + OFF_QUEUE + (size_t)(QTAIL + r - NB) * ND;
      dst[l] = x0; dst[l + 64] = x1; dst[l + 128] = x2; dst[l + 192] = x3;
    }
  } else {
    f32x4 one = {1.f, 1.f, 1.f, 1.f};
    f32x4* lb = (f32x4*)(out + OFF_LABELS);
    const long total4 = (long)NB * LCOLS / 4;  // 8388992, exact
    long stride = (long)(2048 - 512) * 256;
    for (long i = (long)(blk - 512) * 256 + threadIdx.x; i < total4; i += stride)
      __builtin_nontemporal_store(one, lb + i);
  }
}

__global__ __launch_bounds__(64) void kpos(const float* __restrict__ qf32,
                                           float* __restrict__ out,
                                           float* __restrict__ posmin,
                                           float* __restrict__ spos) {
  int b = blockIdx.x, l = threadIdx.x;
  const float* q = qf32 + (size_t)b * ND;
  float q0 = q[l], q1 = q[l + 64], q2 = q[l + 128], q3 = q[l + 192];
  const float* kbase = out + OFF_QUEUE + (size_t)(QTAIL + b * 3) * ND;
  float sp[3];
#pragma unroll
  for (int j = 0; j < 3; j++) {
    const float* kp = kbase + (size_t)j * ND;
    float p = q0 * kp[l] + q1 * kp[l + 64] + q2 * kp[l + 128] + q3 * kp[l + 192];
    sp[j] = wave_sum(p);
  }
  if (l == 0) {
    float* lg = out + (size_t)b * LCOLS;
    float* scr = out + OFF_SCORE + (size_t)b * 7;
#pragma unroll
    for (int j = 0; j < 3; j++) {
      lg[j] = sp[j] / TEMP;
      scr[4 + j] = sp[j];
      spos[b * 3 + j] = sp[j];
    }
    posmin[b] = fminf(sp[0], fminf(sp[1], sp[2]));
  }
}

// round-5 structure (wave-private otile, zero barriers) with ONE change:
// A-fragment loads are fully COALESCED from the pre-swizzled qfrag
// (64 lanes x 16B consecutive per instruction) instead of 16-row-scattered.
__global__ __launch_bounds__(256) void kgemm(const float* __restrict__ queue,
                                             const _Float16* __restrict__ qfrag,
                                             const float* __restrict__ posmin,
                                             float* __restrict__ out,
                                             unsigned short* __restrict__ partials) {
  __shared__ __align__(16) float ot[4][16 * 36];  // per-wave private regions
  // XCD swizzle: adjacent column-blocks share an XCD L2 (512 % 8 == 0)
  int blk = ((int)blockIdx.x & 7) * 64 + ((int)blockIdx.x >> 3);
  int nbase = blk * 128;
  int tid = threadIdx.x;
  int w = tid >> 6, l = tid & 63;
  int r = l & 15, g4 = l >> 4;
  float* otw = ot[w];

  // Phase 0: fused FIFO copy of this block's 128 queue rows (warms L2)
  const f32x4* qp = (const f32x4*)queue;
  f32x4* nq = (f32x4*)(out + OFF_QUEUE);
#pragma unroll
  for (int i = 0; i < 32; i++) {
    int idx = tid + i * 256;          // 128 rows * 64 f32x4
    int row = idx >> 6, c4 = idx & 63;
    int grow = nbase + row;
    f32x4 v = qp[(size_t)grow * 64 + c4];
    if (grow >= 1536)
      __builtin_nontemporal_store(v, nq + (size_t)(grow - 1536) * 64 + c4);
  }

  // Phase 1: per-wave B fragments in registers (32 cols per wave, one-time)
  uint4 bf0[8], bf1[8];
  {
    const float* qrow0 = queue + (size_t)(nbase + w * 32 + r) * ND;
    const float* qrow1 = qrow0 + 16 * ND;
#pragma unroll
    for (int kk = 0; kk < 8; kk++) {
      int k0 = kk * 32 + g4 * 8;
      f32x4 a0 = *(const f32x4*)(qrow0 + k0);
      f32x4 a1 = *(const f32x4*)(qrow0 + k0 + 4);
      f32x4 b0 = *(const f32x4*)(qrow1 + k0);
      f32x4 b1 = *(const f32x4*)(qrow1 + k0 + 4);
      half8 h0, h1;
      h0[0] = (_Float16)a0.x; h0[1] = (_Float16)a0.y; h0[2] = (_Float16)a0.z;
      h0[3] = (_Float16)a0.w; h0[4] = (_Float16)a1.x; h0[5] = (_Float16)a1.y;
      h0[6] = (_Float16)a1.z; h0[7] = (_Float16)a1.w;
      h1[0] = (_Float16)b0.x; h1[1] = (_Float16)b0.y; h1[2] = (_Float16)b0.z;
      h1[3] = (_Float16)b0.w; h1[4] = (_Float16)b1.x; h1[5] = (_Float16)b1.y;
      h1[6] = (_Float16)b1.z; h1[7] = (_Float16)b1.w;
      bf0[kk] = __builtin_bit_cast(uint4, h0);
      bf1[kk] = __builtin_bit_cast(uint4, h1);
    }
  }

  const uint4* ap = (const uint4*)qfrag;  // COALESCED: idx = (mt*8+kk)*64 + l
  const float inv_t = 1.0f / TEMP;
  int rr = l >> 2, qq = l & 3;           // stats: 4 lanes per row

  auto load_af = [&](uint4* dst, int mtv) {
#pragma unroll
    for (int kk = 0; kk < 8; kk++)
      dst[kk] = ap[(size_t)(mtv * 8 + kk) * 64 + l];
  };

  auto body = [&](const uint4* af, int mt) {
    f32x4 acc0 = {0.f, 0.f, 0.f, 0.f}, acc1 = {0.f, 0.f, 0.f, 0.f};
#pragma unroll
    for (int kk = 0; kk < 8; kk++) {
      acc0 = __builtin_amdgcn_mfma_f32_16x16x32_f16(
          __builtin_bit_cast(half8, af[kk]), __builtin_bit_cast(half8, bf0[kk]),
          acc0, 0, 0, 0);
      acc1 = __builtin_amdgcn_mfma_f32_16x16x32_f16(
          __builtin_bit_cast(half8, af[kk]), __builtin_bit_cast(half8, bf1[kk]),
          acc1, 0, 0, 0);
    }
    // wave-private transpose bounce (no barrier; DS is in-order per wave)
#pragma unroll
    for (int j = 0; j < 4; j++) {
      otw[(g4 * 4 + j) * 36 + r] = acc0[j];
      otw[(g4 * 4 + j) * 36 + 16 + r] = acc1[j];
    }
    // logits: 2 rows x 32 cols per instr, 128B segments per 32 lanes
#pragma unroll
    for (int i = 0; i < 8; i++) {
      int row2 = i * 2 + (l >> 5), col = l & 31;
      float v = otw[row2 * 36 + col];
      out[(size_t)(mt * 16 + row2) * LCOLS + 3 + nbase + w * 32 + col] =
          v * inv_t;
    }
    // stats: lane covers 8 cols of row rr; reduce over 4-lane group
    f32x4 s0 = *(const f32x4*)&otw[rr * 36 + qq * 8];
    f32x4 s1 = *(const f32x4*)&otw[rr * 36 + qq * 8 + 4];
    float pm = posmin[mt * 16 + rr];
    float s = s0.x + s0.y + s0.z + s0.w + s1.x + s1.y + s1.z + s1.w;
    float s2 = s0.x * s0.x + s0.y * s0.y + s0.z * s0.z + s0.w * s0.w +
               s1.x * s1.x + s1.y * s1.y + s1.z * s1.z + s1.w * s1.w;
    float mx = fmaxf(fmaxf(fmaxf(s0.x, s0.y), fmaxf(s0.z, s0.w)),
                     fmaxf(fmaxf(s1.x, s1.y), fmaxf(s1.z, s1.w)));
    float c = (s0.x > pm ? 1.f : 0.f) + (s0.y > pm ? 1.f : 0.f) +
              (s0.z > pm ? 1.f : 0.f) + (s0.w > pm ? 1.f : 0.f) +
              (s1.x > pm ? 1.f : 0.f) + (s1.y > pm ? 1.f : 0.f) +
              (s1.z > pm ? 1.f : 0.f) + (s1.w > pm ? 1.f : 0.f);
#pragma unroll
    for (int m = 1; m < 4; m <<= 1) {
      s += __shfl_xor(s, m, 64);
      s2 += __shfl_xor(s2, m, 64);
      c += __shfl_xor(c, m, 64);
      mx = fmaxf(mx, __shfl_xor(mx, m, 64));
    }
    if (qq == 0) {
      us4 p = {f2bf(s), f2bf(s2), f2bf(mx), f2bf(c)};
      // [group][row]: 16 lanes/wave write 128B contiguous
      *(us4*)&partials[((size_t)(blk * 4 + w) * 512 + mt * 16 + rr) * 4] = p;
    }
  };

  uint4 afA[8], afB[8];
  load_af(afA, 0);
#pragma unroll 1
  for (int mt2 = 0; mt2 < 16; mt2++) {
    int mt = mt2 * 2;
    load_af(afB, mt + 1);
    body(afA, mt);
    if (mt2 < 15) load_af(afA, mt + 2);
    body(afB, mt + 1);
  }
}

// combine 2048 bf16 partials per row -> score[:, 0:4]. 64 blocks x 8 rows.
__global__ __launch_bounds__(256) void kreduce(const unsigned short* __restrict__ partials,
                                               const float* __restrict__ spos,
                                               float* __restrict__ out) {
  int r0 = blockIdx.x * 8;
  int tid = threadIdx.x;
  float s[8], s2[8], mx[8], c[8];
#pragma unroll
  for (int j = 0; j < 8; j++) { s[j] = 0.f; s2[j] = 0.f; mx[j] = -2.f; c[j] = 0.f; }
  for (int g = tid; g < 2048; g += 256) {
    const unsigned short* pg = partials + ((size_t)g * 512 + r0) * 4;
#pragma unroll
    for (int j = 0; j < 8; j++) {
      us4 v = *(const us4*)(pg + j * 4);
      s[j] += bf2f(v.x); s2[j] += bf2f(v.y);
      mx[j] = fmaxf(mx[j], bf2f(v.z)); c[j] += bf2f(v.w);
    }
  }
#pragma unroll
  for (int j = 0; j < 8; j++) {
#pragma unroll
    for (int m = 1; m < 64; m <<= 1) {
      s[j] += __shfl_xor(s[j], m, 64);
      s2[j] += __shfl_xor(s2[j], m, 64);
      c[j] += __shfl_xor(c[j], m, 64);
      mx[j] = fmaxf(mx[j], __shfl_xor(mx[j], m, 64));
    }
  }
  __shared__ float red[4][8][4];
  int w = tid >> 6, l = tid & 63;
  if (l == 0) {
#pragma unroll
    for (int j = 0; j < 8; j++) {
      red[w][j][0] = s[j]; red[w][j][1] = s2[j];
      red[w][j][2] = c[j]; red[w][j][3] = mx[j];
    }
  }
  __syncthreads();
  if (tid < 8) {
    int row = r0 + tid;
    float S = 0.f, S2 = 0.f, C = 0.f, M = -2.f;
#pragma unroll
    for (int w2 = 0; w2 < 4; w2++) {
      S += red[w2][tid][0]; S2 += red[w2][tid][1];
      C += red[w2][tid][2]; M = fmaxf(M, red[w2][tid][3]);
    }
    float mean = S / (float)NKQ;
    float var = (S2 - S * S / (float)NKQ) / (float)(NKQ - 1);  // ddof=1
    float cp = 0.f;
#pragma unroll
    for (int j = 0; j < 3; j++) cp += (M > spos[row * 3 + j]) ? 1.f : 0.f;
    float* scr = out + OFF_SCORE + (size_t)row * 7;
    scr[0] = mean; scr[1] = var; scr[2] = C; scr[3] = cp;
  }
}

extern "C" void kernel_launch(void* const* d_in, const int* in_sizes, int n_in,
                              void* d_out, int out_size, void* d_ws, size_t ws_size,
                              hipStream_t stream) {
  const float* query = (const float*)d_in[0];
  const float* key_emb = (const float*)d_in[1];
  const float* queue = (const float*)d_in[2];
  float* out = (float*)d_out;
  _Float16* qfrag = (_Float16*)d_ws;
  float* qf32 = (float*)((char*)d_ws + 262144);
  float* posmin = (float*)((char*)d_ws + 786432);
  float* spos = (float*)((char*)d_ws + 788480);
  unsigned short* partials = (unsigned short*)((char*)d_ws + 1048576);

  kprep<<<2048, 256, 0, stream>>>(query, key_emb, out, qfrag, qf32);
  kpos<<<512, 64, 0, stream>>>(qf32, out, posmin, spos);
  kgemm<<<512, 256, 0, stream>>>(queue, qfrag, posmin, out, partials);
  kreduce<<<64, 256, 0, stream>>>(partials, spos, out);
}